// Round 1
// baseline (941.835 us; speedup 1.0000x reference)
//
#include <hip/hip_runtime.h>
#include <cstdint>
#include <cstddef>

// ---------------------------------------------------------------------------
// TGNN fused pipeline, bf16 MFMA (16x16x32), one block per segment.
//   pairs[P,160] -> embed(aw,bw)[P,384] -> p1[P,512] -> p2[P,256] -> p3[P,1024]
//   -> segment mean [B,1024] -> f1[ B,512] -> f2[B,32] -> f3[B,1]
// P=200000, B=2000, GROUP=100. Tolerance is 2% of max|ref| -> bf16 is safe.
// ws layout (bf16 elements): packed weights then h_pair[2016,1024].
// ---------------------------------------------------------------------------

typedef __bf16 bf16;
typedef __attribute__((ext_vector_type(8))) __bf16 bf16x8;
typedef __attribute__((ext_vector_type(4))) __bf16 bf16x4;
typedef __attribute__((ext_vector_type(4))) float floatx4;

#define GRP 100
#define MT 7            // 7 m-tiles of 16 rows = 112 (100 valid + 12 pad)

// packed-ws element offsets (bf16 elements)
#define WOFF_AW 0
#define WOFF_BW 8192
#define WOFF_P1 12288
#define WOFF_P2 208896
#define WOFF_P3 339968
#define WOFF_F1 602112
#define WOFF_F2 1126400
#define WOFF_HP 1142784   // h_pair [2016][1024] bf16

// LDS strides (elements). All %8==0 (16B-aligned b128 reads) and
// (stride/2)%32 in {4,20} -> only 2-way bank aliasing (free on CDNA4).
#define LSTR_P  168
#define LSTR_H  392
#define LSTR_H2 136
#define LSTR_H3 264

// ---------------------------------------------------------------------------
// Weight repack: fp32 row-major [K][N] -> bf16 fragment-order
// dst[((nc*KT + kt)*CW + nl)*32 + kk] = src[(kt*32+kk)*N + nc*CW + nl]
// ---------------------------------------------------------------------------
__global__ void pack_w(const float* __restrict__ src, bf16* __restrict__ dst,
                       int K, int N, int CW) {
  int total = K * N;
  int KT = K >> 5;
  for (int i = blockIdx.x * blockDim.x + threadIdx.x; i < total;
       i += gridDim.x * blockDim.x) {
    int kk = i & 31;
    int t  = i >> 5;
    int nl = t % CW;
    int t2 = t / CW;
    int kt = t2 % KT;
    int nc = t2 / KT;
    dst[i] = (bf16)src[(kt * 32 + kk) * N + nc * CW + nl];
  }
}

// one k-step: 2 B-frag loads + 7 A-frag loads -> 14 MFMAs
static __device__ __forceinline__ void kstep(const bf16* __restrict__ A,
                                             int astride, int acol,
                                             const bf16* __restrict__ bs,
                                             floatx4* acc, int S, int jb,
                                             int lm, int lq, int w) {
  bf16x8 b0 = *(const bf16x8*)(bs + (w * 16 + lm) * 32 + lq * 8);
  bf16x8 b1 = *(const bf16x8*)(bs + ((w + 4) * 16 + lm) * 32 + lq * 8);
#pragma unroll
  for (int mt = 0; mt < MT; ++mt) {
    bf16x8 a = *(const bf16x8*)(A + (mt * 16 + lm) * astride + acol + lq * 8);
    acc[mt * S + jb] =
        __builtin_amdgcn_mfma_f32_16x16x32_bf16(a, b0, acc[mt * S + jb], 0, 0, 0);
    acc[mt * S + jb + 1] =
        __builtin_amdgcn_mfma_f32_16x16x32_bf16(a, b1, acc[mt * S + jb + 1], 0, 0, 0);
  }
}

// ---------------------------------------------------------------------------
// One block per segment: full per-pair MLP + masked segment sum.
// LDS: hbuf 87.8K | pbuf 37.6K (pairs, later h2-chunk) | bs 8K | sumx 4K
//      = 137,728 B -> 1 block/CU.
// ---------------------------------------------------------------------------
__global__ __launch_bounds__(256, 1) void seg_kernel(
    const float* __restrict__ pairs, const int* __restrict__ idxp,
    const float* __restrict__ ab, const float* __restrict__ bb,
    const float* __restrict__ p1b, const float* __restrict__ p2b,
    const float* __restrict__ p3b, const bf16* __restrict__ wpk,
    bf16* __restrict__ hpair) {
  __shared__ __align__(16) bf16 hbuf[112 * LSTR_H];   // h[112,384] then h3[112,256]
  __shared__ __align__(16) bf16 pbuf[112 * LSTR_P];   // pairs bf16, then h2 chunk
  __shared__ __align__(16) bf16 bs[4096];             // 8KB B slab [128 cols][32 k]
  __shared__ float sumx[1024];

  const int tid = threadIdx.x;
  const int w = tid >> 6;
  const int lane = tid & 63;
  const int lm = lane & 15;
  const int lq = lane >> 4;
  const int seg = blockIdx.x;

  // ---- load pairs tile [100,160] fp32 -> bf16 LDS, zero pad rows ----
  {
    const float4* src = (const float4*)(pairs + (size_t)seg * (GRP * 160));
    for (int i = tid; i < 4000; i += 256) {
      int row = i / 40;
      int c4 = (i - row * 40) * 4;
      float4 v = src[i];
      bf16x4 o = {(bf16)v.x, (bf16)v.y, (bf16)v.z, (bf16)v.w};
      *(bf16x4*)(pbuf + row * LSTR_P + c4) = o;
    }
    for (int i = tid; i < 12 * 160; i += 256) {
      int row = 100 + i / 160;
      int c = i - (i / 160) * 160;
      pbuf[row * LSTR_P + c] = (bf16)0.0f;
    }
  }

  bf16x8* const bsv = (bf16x8*)bs;
  const floatx4 fz = {0.f, 0.f, 0.f, 0.f};
  floatx4 acc[14];
  floatx4 acc3[28];
  bf16x8 r0, r1;

  // ---------------- embed: a1 / a2 / be -> hbuf[112,384] ----------------
#pragma unroll
  for (int sub = 0; sub < 3; ++sub) {
    const int acol = (sub == 0) ? 0 : (sub == 1) ? 64 : 128;
    const int KT = (sub == 2) ? 1 : 2;
    const bf16* wsrc = wpk + ((sub == 2) ? WOFF_BW : WOFF_AW);
    const int ocol = sub * 128;
    const float* bias = (sub == 2) ? bb : ab;
#pragma unroll
    for (int t = 0; t < 14; ++t) acc[t] = fz;
    { const bf16x8* s_ = (const bf16x8*)wsrc; r0 = s_[tid]; r1 = s_[tid + 256]; }
    for (int kt = 0; kt < KT; ++kt) {
      __syncthreads();
      bsv[tid] = r0; bsv[tid + 256] = r1;
      __syncthreads();
      if (kt + 1 < KT) {
        const bf16x8* s_ = (const bf16x8*)(wsrc + (size_t)(kt + 1) * 4096);
        r0 = s_[tid]; r1 = s_[tid + 256];
      }
      kstep(pbuf, LSTR_P, acol + kt * 32, bs, acc, 2, 0, lm, lq, w);
    }
#pragma unroll
    for (int mt = 0; mt < MT; ++mt)
#pragma unroll
      for (int j = 0; j < 2; ++j) {
        int col = (w + 4 * j) * 16 + lm;
        float bv = bias[col];
        floatx4 c = acc[mt * 2 + j];
#pragma unroll
        for (int r = 0; r < 4; ++r) {
          float v = c[r] + bv;
          v = v > 0.f ? v : 0.f;
          hbuf[(mt * 16 + lq * 4 + r) * LSTR_H + ocol + col] = (bf16)v;
        }
      }
  }

  // ------- p1 (N=512 in 4 chunks), each chunk fused into p2 K-accum -------
#pragma unroll
  for (int t = 0; t < 28; ++t) acc3[t] = fz;

  for (int nc = 0; nc < 4; ++nc) {
#pragma unroll
    for (int t = 0; t < 14; ++t) acc[t] = fz;
    { const bf16x8* s_ = (const bf16x8*)(wpk + WOFF_P1 + (size_t)nc * 12 * 4096);
      r0 = s_[tid]; r1 = s_[tid + 256]; }
    for (int kt = 0; kt < 12; ++kt) {
      __syncthreads();
      bsv[tid] = r0; bsv[tid + 256] = r1;
      __syncthreads();
      if (kt + 1 < 12) {
        const bf16x8* s_ =
            (const bf16x8*)(wpk + WOFF_P1 + ((size_t)nc * 12 + kt + 1) * 4096);
        r0 = s_[tid]; r1 = s_[tid + 256];
      }
      kstep(hbuf, LSTR_H, kt * 32, bs, acc, 2, 0, lm, lq, w);
    }
    // p1 epilogue -> h2 chunk in pbuf (stride 136), cols nc*128..
#pragma unroll
    for (int mt = 0; mt < MT; ++mt)
#pragma unroll
      for (int j = 0; j < 2; ++j) {
        int col = (w + 4 * j) * 16 + lm;
        float bv = p1b[nc * 128 + col];
        floatx4 c = acc[mt * 2 + j];
#pragma unroll
        for (int r = 0; r < 4; ++r) {
          float v = c[r] + bv;
          v = v > 0.f ? v : 0.f;
          pbuf[(mt * 16 + lq * 4 + r) * LSTR_H2 + col] = (bf16)v;
        }
      }
    // p2 partial over this 128-wide K slice (4 k-tiles x 2 N-halves)
    { const bf16x8* s_ = (const bf16x8*)(wpk + WOFF_P2 + (size_t)(nc * 4) * 4096);
      r0 = s_[tid]; r1 = s_[tid + 256]; }
#pragma unroll
    for (int s = 0; s < 8; ++s) {
      const int kt2 = s >> 1, h = s & 1;
      __syncthreads();
      bsv[tid] = r0; bsv[tid + 256] = r1;
      __syncthreads();
      if (s + 1 < 8) {
        int s2 = s + 1;
        int slab = (s2 & 1) * 16 + nc * 4 + (s2 >> 1);
        const bf16x8* s_ = (const bf16x8*)(wpk + WOFF_P2 + (size_t)slab * 4096);
        r0 = s_[tid]; r1 = s_[tid + 256];
      }
      kstep(pbuf, LSTR_H2, kt2 * 32, bs, acc3, 4, 2 * h, lm, lq, w);
    }
  }

  // p2 epilogue: h3 = relu(acc3 + p2b) -> hbuf (stride 264)
  __syncthreads();
#pragma unroll
  for (int mt = 0; mt < MT; ++mt)
#pragma unroll
    for (int s = 0; s < 4; ++s) {
      int col = (w + 4 * s) * 16 + lm;
      float bv = p2b[col];
      floatx4 c = acc3[mt * 4 + s];
#pragma unroll
      for (int r = 0; r < 4; ++r) {
        float v = c[r] + bv;
        v = v > 0.f ? v : 0.f;
        hbuf[(mt * 16 + lq * 4 + r) * LSTR_H3 + col] = (bf16)v;
      }
    }

  // ---------------- p3 (N=1024 in 8 chunks) + masked column sum ----------
  const float cnt = (float)idxp[seg];
  for (int nc = 0; nc < 8; ++nc) {
#pragma unroll
    for (int t = 0; t < 14; ++t) acc[t] = fz;
    { const bf16x8* s_ = (const bf16x8*)(wpk + WOFF_P3 + (size_t)nc * 8 * 4096);
      r0 = s_[tid]; r1 = s_[tid + 256]; }
    for (int kt = 0; kt < 8; ++kt) {
      __syncthreads();
      bsv[tid] = r0; bsv[tid + 256] = r1;
      __syncthreads();
      if (kt + 1 < 8) {
        const bf16x8* s_ =
            (const bf16x8*)(wpk + WOFF_P3 + ((size_t)nc * 8 + kt + 1) * 4096);
        r0 = s_[tid]; r1 = s_[tid + 256];
      }
      kstep(hbuf, LSTR_H3, kt * 32, bs, acc, 2, 0, lm, lq, w);
    }
    // column sums over valid rows (<100): mt<6 all rows, mt==6 only lq==0
#pragma unroll
    for (int j = 0; j < 2; ++j) {
      float cs = 0.f;
#pragma unroll
      for (int mt = 0; mt < MT; ++mt) {
        floatx4 c = acc[mt * 2 + j];
        float t4 = c[0] + c[1] + c[2] + c[3];
        if (mt == 6 && lq != 0) t4 = 0.f;
        cs += t4;
      }
      cs += __shfl_xor(cs, 16, 64);
      cs += __shfl_xor(cs, 32, 64);
      if (lq == 0) sumx[nc * 128 + (w + 4 * j) * 16 + lm] = cs;
    }
  }
  __syncthreads();
  for (int c = tid; c < 1024; c += 256) {
    float hp = sumx[c] / cnt + p3b[c];  // bias folded in after the mean
    hpair[(size_t)seg * 1024 + c] = (bf16)hp;
  }
}

// ---------------------------------------------------------------------------
// Head MLP: h_pair[2000,1024] -> f1(512,relu) -> f2(32,relu) -> f3(1).
// One wave per 16 rows; 2 waves/block; grid 63 (covers 2016 rows, stores
// guarded at 2000). B-frags straight from packed global (L2-hot).
// ---------------------------------------------------------------------------
__global__ __launch_bounds__(128, 1) void head_kernel(
    const bf16* __restrict__ wpk, const bf16* __restrict__ hpair,
    const float* __restrict__ f1b, const float* __restrict__ f2b,
    const float* __restrict__ f3w, const float* __restrict__ f3b,
    float* __restrict__ out) {
  __shared__ __align__(16) bf16 h2s[2 * 16 * 520];
  __shared__ __align__(16) bf16 h3s[2 * 16 * 40];

  const int tid = threadIdx.x;
  const int wv = tid >> 6;
  const int lane = tid & 63;
  const int lm = lane & 15;
  const int lq = lane >> 4;
  const int r0 = (blockIdx.x * 2 + wv) * 16;

  bf16* h2 = h2s + wv * 16 * 520;
  bf16* h3 = h3s + wv * 16 * 40;
  const bf16* wf1 = wpk + WOFF_F1;
  const bf16* wf2 = wpk + WOFF_F2;
  const floatx4 fz = {0.f, 0.f, 0.f, 0.f};

  // ---- f1: [16,1024] @ [1024,512] ----
  for (int nc = 0; nc < 4; ++nc) {
    floatx4 a8[8];
#pragma unroll
    for (int t = 0; t < 8; ++t) a8[t] = fz;
    for (int kt = 0; kt < 32; ++kt) {
      bf16x8 a = *(const bf16x8*)(hpair + (size_t)(r0 + lm) * 1024 + kt * 32 + lq * 8);
#pragma unroll
      for (int nt = 0; nt < 8; ++nt) {
        bf16x8 b = *(const bf16x8*)(wf1 +
                      ((size_t)(nc * 32 + kt) * 128 + nt * 16 + lm) * 32 + lq * 8);
        a8[nt] = __builtin_amdgcn_mfma_f32_16x16x32_bf16(a, b, a8[nt], 0, 0, 0);
      }
    }
#pragma unroll
    for (int nt = 0; nt < 8; ++nt) {
      int col = nc * 128 + nt * 16 + lm;
      float bv = f1b[col];
      floatx4 c = a8[nt];
#pragma unroll
      for (int r = 0; r < 4; ++r) {
        float v = c[r] + bv;
        v = v > 0.f ? v : 0.f;
        h2[(lq * 4 + r) * 520 + col] = (bf16)v;
      }
    }
  }

  // ---- f2: [16,512] @ [512,32] ----  (same-wave LDS producer/consumer)
  floatx4 c2[2];
  c2[0] = fz; c2[1] = fz;
  for (int kt = 0; kt < 16; ++kt) {
    bf16x8 a = *(const bf16x8*)(h2 + lm * 520 + kt * 32 + lq * 8);
#pragma unroll
    for (int j = 0; j < 2; ++j) {
      bf16x8 b = *(const bf16x8*)(wf2 + ((size_t)kt * 32 + j * 16 + lm) * 32 + lq * 8);
      c2[j] = __builtin_amdgcn_mfma_f32_16x16x32_bf16(a, b, c2[j], 0, 0, 0);
    }
  }
#pragma unroll
  for (int j = 0; j < 2; ++j) {
    int col = j * 16 + lm;
    float bv = f2b[col];
#pragma unroll
    for (int r = 0; r < 4; ++r) {
      float v = c2[j][r] + bv;
      v = v > 0.f ? v : 0.f;
      h3[(lq * 4 + r) * 40 + col] = (bf16)v;
    }
  }

  // ---- f3: [16,32] @ [32,1] via VALU + wave reduce ----
  float ps = 0.f;
#pragma unroll
  for (int jj = 0; jj < 8; ++jj)
    ps += (float)h3[lm * 40 + lq * 8 + jj] * f3w[lq * 8 + jj];
  ps += __shfl_xor(ps, 16, 64);
  ps += __shfl_xor(ps, 32, 64);
  if (lq == 0) {
    int row = r0 + lm;
    if (row < 2000) out[row] = ps + f3b[0];
  }
}

// ---------------------------------------------------------------------------
extern "C" void kernel_launch(void* const* d_in, const int* in_sizes, int n_in,
                              void* d_out, int out_size, void* d_ws,
                              size_t ws_size, hipStream_t stream) {
  (void)in_sizes; (void)n_in; (void)out_size; (void)ws_size;
  const float* pairs = (const float*)d_in[0];
  const int*   idxp  = (const int*)d_in[1];
  // d_in[2] = ref_feats (unused by the reference)
  const float* aw  = (const float*)d_in[3];
  const float* ab  = (const float*)d_in[4];
  const float* bw  = (const float*)d_in[5];
  const float* bb  = (const float*)d_in[6];
  const float* p1w = (const float*)d_in[7];
  const float* p1b = (const float*)d_in[8];
  const float* p2w = (const float*)d_in[9];
  const float* p2b = (const float*)d_in[10];
  const float* p3w = (const float*)d_in[11];
  const float* p3b = (const float*)d_in[12];
  const float* f1w = (const float*)d_in[13];
  const float* f1b = (const float*)d_in[14];
  const float* f2w = (const float*)d_in[15];
  const float* f2b = (const float*)d_in[16];
  const float* f3w = (const float*)d_in[17];
  const float* f3b = (const float*)d_in[18];

  bf16* wpk = (bf16*)d_ws;

  pack_w<<<32, 256, 0, stream>>>(aw,  wpk + WOFF_AW, 64, 128, 128);
  pack_w<<<16, 256, 0, stream>>>(bw,  wpk + WOFF_BW, 32, 128, 128);
  pack_w<<<768, 256, 0, stream>>>(p1w, wpk + WOFF_P1, 384, 512, 128);
  pack_w<<<512, 256, 0, stream>>>(p2w, wpk + WOFF_P2, 512, 256, 128);
  pack_w<<<1024, 256, 0, stream>>>(p3w, wpk + WOFF_P3, 256, 1024, 128);
  pack_w<<<2048, 256, 0, stream>>>(f1w, wpk + WOFF_F1, 1024, 512, 128);
  pack_w<<<64, 256, 0, stream>>>(f2w, wpk + WOFF_F2, 512, 32, 32);

  seg_kernel<<<2000, 256, 0, stream>>>(pairs, idxp, ab, bb, p1b, p2b, p3b,
                                       wpk, wpk + WOFF_HP);
  head_kernel<<<63, 128, 0, stream>>>(wpk, wpk + WOFF_HP, f1b, f2b, f3w, f3b,
                                      (float*)d_out);
}

// Round 2
// 619.327 us; speedup vs baseline: 1.5207x; 1.5207x over previous
//
#include <hip/hip_runtime.h>
#include <cstdint>
#include <cstddef>

// ---------------------------------------------------------------------------
// TGNN fused pipeline v2.
//  - B-fragments read straight from packed global weights (L2-hot, coalesced)
//    -> no per-kstep LDS staging, no per-kstep barriers.
//  - One block per HALF-segment (50 rows, M=64, 4 m-tiles): LDS 71.7 KB ->
//    2 blocks/CU (8 waves). Partial column sums to ws, combined by a tiny
//    kernel into h_pair.
//  - Head: 125 blocks x 4 waves, wave-per-128-cols of f1.
// ---------------------------------------------------------------------------

typedef __bf16 bf16;
typedef __attribute__((ext_vector_type(8))) __bf16 bf16x8;
typedef __attribute__((ext_vector_type(4))) __bf16 bf16x4;
typedef __attribute__((ext_vector_type(4))) float floatx4;

#define GRP 100
#define RH 50           // rows per half-segment

// packed-ws element offsets (bf16 elements)
#define WOFF_AW 0
#define WOFF_BW 8192
#define WOFF_P1 12288
#define WOFF_P2 208896
#define WOFF_P3 339968
#define WOFF_F1 602112
#define WOFF_F2 1126400
#define WOFF_PS 1142784          // partial sums [4000][1024] bf16
#define WOFF_HP 5238784          // h_pair [2000][1024] bf16

// LDS strides (bf16 elems): %8==0 (16B rows) and (stride/2)%32==4 or 20
// -> at most 2-way bank aliasing across the 16 lm-lanes (free on CDNA4).
#define LSTR_P  168
#define LSTR_H  392
#define LSTR_H2 136
#define LSTR_H3 264

// ---------------------------------------------------------------------------
// Weight repack: fp32 row-major [K][N] -> bf16 fragment-order
// dst[((nc*KT + kt)*CW + nl)*32 + kk] = src[(kt*32+kk)*N + nc*CW + nl]
// ---------------------------------------------------------------------------
__global__ void pack_w(const float* __restrict__ src, bf16* __restrict__ dst,
                       int K, int N, int CW) {
  int total = K * N;
  int KT = K >> 5;
  for (int i = blockIdx.x * blockDim.x + threadIdx.x; i < total;
       i += gridDim.x * blockDim.x) {
    int kk = i & 31;
    int t  = i >> 5;
    int nl = t % CW;
    int t2 = t / CW;
    int kt = t2 % KT;
    int nc = t2 / KT;
    dst[i] = (bf16)src[(kt * 32 + kk) * N + nc * CW + nl];
  }
}

static __device__ __forceinline__ floatx4 mfma16(bf16x8 a, bf16x8 b, floatx4 c) {
  return __builtin_amdgcn_mfma_f32_16x16x32_bf16(a, b, c, 0, 0, 0);
}

// kstep, 2 B-frags from global: 4 A-reads, 8 MFMA
static __device__ __forceinline__ void kstep2(const bf16* __restrict__ Ab,
                                              int astride, int acol,
                                              const bf16* __restrict__ b0p,
                                              const bf16* __restrict__ b1p,
                                              floatx4* acc, int lm, int lq) {
  bf16x8 b0 = *(const bf16x8*)b0p;
  bf16x8 b1 = *(const bf16x8*)b1p;
#pragma unroll
  for (int mt = 0; mt < 4; ++mt) {
    bf16x8 a = *(const bf16x8*)(Ab + (mt * 16 + lm) * astride + acol + lq * 8);
    acc[mt * 2]     = mfma16(a, b0, acc[mt * 2]);
    acc[mt * 2 + 1] = mfma16(a, b1, acc[mt * 2 + 1]);
  }
}

// kstep, 4 B-frags from global (consecutive 16-col frags): 4 A-reads, 16 MFMA
static __device__ __forceinline__ void kstep4(const bf16* __restrict__ Ab,
                                              int astride, int acol,
                                              const bf16* __restrict__ bp,
                                              floatx4* acc, int lm, int lq) {
  bf16x8 bf[4];
#pragma unroll
  for (int j = 0; j < 4; ++j) bf[j] = *(const bf16x8*)(bp + j * 512);
#pragma unroll
  for (int mt = 0; mt < 4; ++mt) {
    bf16x8 a = *(const bf16x8*)(Ab + (mt * 16 + lm) * astride + acol + lq * 8);
#pragma unroll
    for (int j = 0; j < 4; ++j)
      acc[mt * 4 + j] = mfma16(a, bf[j], acc[mt * 4 + j]);
  }
}

// epilogue for 2-N-tile acc: relu(acc+bias) -> LDS (dst pre-offset by ocol)
static __device__ __forceinline__ void epi2(const floatx4* acc,
                                            const float* __restrict__ bias,
                                            bf16* dst, int dstride, int w,
                                            int lm, int lq) {
#pragma unroll
  for (int mt = 0; mt < 4; ++mt)
#pragma unroll
    for (int j = 0; j < 2; ++j) {
      int col = (w + 4 * j) * 16 + lm;
      float bv = bias[col];
      floatx4 c = acc[mt * 2 + j];
#pragma unroll
      for (int r = 0; r < 4; ++r) {
        float v = c[r] + bv;
        v = v > 0.f ? v : 0.f;
        dst[(mt * 16 + lq * 4 + r) * dstride + col] = (bf16)v;
      }
    }
}

// ---------------------------------------------------------------------------
// One block per half-segment. LDS: hbuf 50176 + pbuf 21504 = 71680 B.
// ---------------------------------------------------------------------------
__global__ __launch_bounds__(256, 2) void seg_kernel(
    const float* __restrict__ pairs, const float* __restrict__ ab,
    const float* __restrict__ bb, const float* __restrict__ p1b,
    const float* __restrict__ p2b, const bf16* __restrict__ wpk,
    bf16* __restrict__ psum) {
  __shared__ __align__(16) bf16 hbuf[64 * LSTR_H];  // h[64,384] then h3[64,256]
  __shared__ __align__(16) bf16 pbuf[64 * LSTR_P];  // pairs bf16, then h2 chunk

  const int tid = threadIdx.x;
  const int w = tid >> 6;
  const int lane = tid & 63;
  const int lm = lane & 15;
  const int lq = lane >> 4;
  const int blk = blockIdx.x;

  // ---- stage pairs half-tile [50,160] fp32 -> bf16 LDS, zero pad rows ----
  {
    const float4* src = (const float4*)(pairs + (size_t)blk * (RH * 160));
    for (int i = tid; i < RH * 40; i += 256) {
      int row = i / 40;
      int c4 = (i - row * 40) * 4;
      float4 v = src[i];
      bf16x4 o = {(bf16)v.x, (bf16)v.y, (bf16)v.z, (bf16)v.w};
      *(bf16x4*)(pbuf + row * LSTR_P + c4) = o;
    }
    for (int i = tid; i < 14 * 160; i += 256) {
      int row = RH + i / 160;
      int c = i - (i / 160) * 160;
      pbuf[row * LSTR_P + c] = (bf16)0.0f;
    }
  }
  __syncthreads();

  const floatx4 fz = {0.f, 0.f, 0.f, 0.f};
  floatx4 acc[16];
  floatx4 acc3[16];

  // ---------------- embed: a1 / a2 / be -> hbuf[64,384] ----------------
  // a1: K=64 from pairs cols 0..63
#pragma unroll
  for (int t = 0; t < 8; ++t) acc[t] = fz;
#pragma unroll
  for (int kt = 0; kt < 2; ++kt)
    kstep2(pbuf, LSTR_P, kt * 32,
           wpk + WOFF_AW + ((size_t)(kt * 128 + w * 16 + lm)) * 32 + lq * 8,
           wpk + WOFF_AW + ((size_t)(kt * 128 + (w + 4) * 16 + lm)) * 32 + lq * 8,
           acc, lm, lq);
  epi2(acc, ab, hbuf, LSTR_H, w, lm, lq);
  // a2: K=64 from pairs cols 64..127
#pragma unroll
  for (int t = 0; t < 8; ++t) acc[t] = fz;
#pragma unroll
  for (int kt = 0; kt < 2; ++kt)
    kstep2(pbuf, LSTR_P, 64 + kt * 32,
           wpk + WOFF_AW + ((size_t)(kt * 128 + w * 16 + lm)) * 32 + lq * 8,
           wpk + WOFF_AW + ((size_t)(kt * 128 + (w + 4) * 16 + lm)) * 32 + lq * 8,
           acc, lm, lq);
  epi2(acc, ab, hbuf + 128, LSTR_H, w, lm, lq);
  // be: K=32 from pairs cols 128..159
#pragma unroll
  for (int t = 0; t < 8; ++t) acc[t] = fz;
  kstep2(pbuf, LSTR_P, 128,
         wpk + WOFF_BW + ((size_t)(w * 16 + lm)) * 32 + lq * 8,
         wpk + WOFF_BW + ((size_t)((w + 4) * 16 + lm)) * 32 + lq * 8,
         acc, lm, lq);
  epi2(acc, bb, hbuf + 256, LSTR_H, w, lm, lq);

  __syncthreads();

  // ------- p1 (4 N-chunks of 128), each fused into p2 K-accumulation -------
#pragma unroll
  for (int t = 0; t < 16; ++t) acc3[t] = fz;

  for (int nc = 0; nc < 4; ++nc) {
#pragma unroll
    for (int t = 0; t < 8; ++t) acc[t] = fz;
#pragma unroll
    for (int kt = 0; kt < 12; ++kt)
      kstep2(hbuf, LSTR_H, kt * 32,
             wpk + WOFF_P1 + ((size_t)((nc * 12 + kt) * 128 + w * 16 + lm)) * 32 + lq * 8,
             wpk + WOFF_P1 + ((size_t)((nc * 12 + kt) * 128 + (w + 4) * 16 + lm)) * 32 + lq * 8,
             acc, lm, lq);
    __syncthreads();                       // prior p2 reads of pbuf done
    epi2(acc, p1b + nc * 128, pbuf, LSTR_H2, w, lm, lq);
    __syncthreads();                       // h2 chunk visible
#pragma unroll
    for (int kt2 = 0; kt2 < 4; ++kt2)
      kstep4(pbuf, LSTR_H2, kt2 * 32,
             wpk + WOFF_P2 +
                 ((size_t)(((w >> 1) * 16 + nc * 4 + kt2) * 128 + (w & 1) * 64 + lm)) * 32 +
                 lq * 8,
             acc3, lm, lq);
  }

  // p2 epilogue: h3 = relu(acc3 + p2b) -> hbuf (stride 264). All p1 hbuf
  // reads completed at the last barrier; p2 ksteps only touch pbuf.
#pragma unroll
  for (int mt = 0; mt < 4; ++mt)
#pragma unroll
    for (int s = 0; s < 4; ++s) {
      int col = w * 64 + s * 16 + lm;
      float bv = p2b[col];
      floatx4 c = acc3[mt * 4 + s];
#pragma unroll
      for (int r = 0; r < 4; ++r) {
        float v = c[r] + bv;
        v = v > 0.f ? v : 0.f;
        hbuf[(mt * 16 + lq * 4 + r) * LSTR_H3 + col] = (bf16)v;
      }
    }
  __syncthreads();

  // ---------------- p3 (4 N-chunks of 256) + masked column sums ----------
  const int wn = w >> 1;
  const int wl = (w & 1) * 64;
  for (int c = 0; c < 4; ++c) {
#pragma unroll
    for (int t = 0; t < 16; ++t) acc[t] = fz;
#pragma unroll
    for (int kt = 0; kt < 8; ++kt)
      kstep4(hbuf, LSTR_H3, kt * 32,
             wpk + WOFF_P3 + ((size_t)(((2 * c + wn) * 8 + kt) * 128 + wl + lm)) * 32 + lq * 8,
             acc, lm, lq);
    // column sums over valid rows (0..49): mt<3 full, mt==3 rows 48,49 only
#pragma unroll
    for (int j = 0; j < 4; ++j) {
      float cs = 0.f;
#pragma unroll
      for (int mt = 0; mt < 4; ++mt) {
        floatx4 cc = acc[mt * 4 + j];
        float t4;
        if (mt < 3) t4 = cc[0] + cc[1] + cc[2] + cc[3];
        else        t4 = (lq == 0) ? (cc[0] + cc[1]) : 0.f;
        cs += t4;
      }
      cs += __shfl_xor(cs, 16, 64);
      cs += __shfl_xor(cs, 32, 64);
      if (lq == 0) {
        int col = c * 256 + w * 64 + j * 16 + lm;
        psum[(size_t)blk * 1024 + col] = (bf16)cs;
      }
    }
  }
}

// ---------------------------------------------------------------------------
// Combine the two half-segment partial sums -> h_pair bf16 (mean + bias)
// ---------------------------------------------------------------------------
__global__ void combine_kernel(const bf16* __restrict__ psum,
                               const int* __restrict__ idxp,
                               const float* __restrict__ p3b,
                               bf16* __restrict__ hpair) {
  int i = blockIdx.x * 256 + threadIdx.x;
  if (i >= 2000 * 1024) return;
  int seg = i >> 10;
  int c = i & 1023;
  float s = (float)psum[(size_t)(2 * seg) * 1024 + c] +
            (float)psum[(size_t)(2 * seg + 1) * 1024 + c];
  float hp = s / (float)idxp[seg] + p3b[c];
  hpair[i] = (bf16)hp;
}

// ---------------------------------------------------------------------------
// Head MLP: 125 blocks x 4 waves; block handles 16 rows; wave w does f1 cols
// w*128..+127; wave 0 finishes f2 (32 cols) + f3.
// ---------------------------------------------------------------------------
__global__ __launch_bounds__(256, 2) void head_kernel(
    const bf16* __restrict__ wpk, const bf16* __restrict__ hpair,
    const float* __restrict__ f1b, const float* __restrict__ f2b,
    const float* __restrict__ f3w, const float* __restrict__ f3b,
    float* __restrict__ out) {
  __shared__ __align__(16) bf16 h2[16 * 520];
  __shared__ __align__(16) bf16 h3[16 * 40];

  const int tid = threadIdx.x;
  const int w = tid >> 6;
  const int lane = tid & 63;
  const int lm = lane & 15;
  const int lq = lane >> 4;
  const int r0 = blockIdx.x * 16;
  const bf16* wf1 = wpk + WOFF_F1;
  const floatx4 fz = {0.f, 0.f, 0.f, 0.f};

  // ---- f1: [16,1024] @ [1024,128-per-wave] ----
  floatx4 a8[8];
#pragma unroll
  for (int t = 0; t < 8; ++t) a8[t] = fz;
#pragma unroll 4
  for (int kt = 0; kt < 32; ++kt) {
    bf16x8 a = *(const bf16x8*)(hpair + (size_t)(r0 + lm) * 1024 + kt * 32 + lq * 8);
#pragma unroll
    for (int nt = 0; nt < 8; ++nt) {
      bf16x8 b = *(const bf16x8*)(wf1 +
                    ((size_t)((w * 32 + kt) * 128 + nt * 16 + lm)) * 32 + lq * 8);
      a8[nt] = mfma16(a, b, a8[nt]);
    }
  }
#pragma unroll
  for (int nt = 0; nt < 8; ++nt) {
    int col = w * 128 + nt * 16 + lm;
    float bv = f1b[col];
    floatx4 c = a8[nt];
#pragma unroll
    for (int r = 0; r < 4; ++r) {
      float v = c[r] + bv;
      v = v > 0.f ? v : 0.f;
      h2[(lq * 4 + r) * 520 + col] = (bf16)v;
    }
  }
  __syncthreads();

  // ---- f2 + f3 on wave 0 ----
  if (w == 0) {
    floatx4 c2[2];
    c2[0] = fz; c2[1] = fz;
#pragma unroll
    for (int kt = 0; kt < 16; ++kt) {
      bf16x8 a = *(const bf16x8*)(h2 + lm * 520 + kt * 32 + lq * 8);
#pragma unroll
      for (int j = 0; j < 2; ++j) {
        bf16x8 b = *(const bf16x8*)(wpk + WOFF_F2 +
                      ((size_t)(kt * 32 + j * 16 + lm)) * 32 + lq * 8);
        c2[j] = mfma16(a, b, c2[j]);
      }
    }
#pragma unroll
    for (int j = 0; j < 2; ++j) {
      int col = j * 16 + lm;
      float bv = f2b[col];
#pragma unroll
      for (int r = 0; r < 4; ++r) {
        float v = c2[j][r] + bv;
        v = v > 0.f ? v : 0.f;
        h3[(lq * 4 + r) * 40 + col] = (bf16)v;
      }
    }
    float ps = 0.f;
#pragma unroll
    for (int jj = 0; jj < 8; ++jj)
      ps += (float)h3[lm * 40 + lq * 8 + jj] * f3w[lq * 8 + jj];
    ps += __shfl_xor(ps, 16, 64);
    ps += __shfl_xor(ps, 32, 64);
    if (lq == 0) out[r0 + lm] = ps + f3b[0];
  }
}

// ---------------------------------------------------------------------------
extern "C" void kernel_launch(void* const* d_in, const int* in_sizes, int n_in,
                              void* d_out, int out_size, void* d_ws,
                              size_t ws_size, hipStream_t stream) {
  (void)in_sizes; (void)n_in; (void)out_size; (void)ws_size;
  const float* pairs = (const float*)d_in[0];
  const int*   idxp  = (const int*)d_in[1];
  // d_in[2] = ref_feats (unused by the reference)
  const float* aw  = (const float*)d_in[3];
  const float* ab  = (const float*)d_in[4];
  const float* bw  = (const float*)d_in[5];
  const float* bb  = (const float*)d_in[6];
  const float* p1w = (const float*)d_in[7];
  const float* p1b = (const float*)d_in[8];
  const float* p2w = (const float*)d_in[9];
  const float* p2b = (const float*)d_in[10];
  const float* p3w = (const float*)d_in[11];
  const float* p3b = (const float*)d_in[12];
  const float* f1w = (const float*)d_in[13];
  const float* f1b = (const float*)d_in[14];
  const float* f2w = (const float*)d_in[15];
  const float* f2b = (const float*)d_in[16];
  const float* f3w = (const float*)d_in[17];
  const float* f3b = (const float*)d_in[18];

  bf16* wpk = (bf16*)d_ws;

  pack_w<<<32, 256, 0, stream>>>(aw,  wpk + WOFF_AW, 64, 128, 128);
  pack_w<<<16, 256, 0, stream>>>(bw,  wpk + WOFF_BW, 32, 128, 128);
  pack_w<<<768, 256, 0, stream>>>(p1w, wpk + WOFF_P1, 384, 512, 128);
  pack_w<<<512, 256, 0, stream>>>(p2w, wpk + WOFF_P2, 512, 256, 128);
  pack_w<<<1024, 256, 0, stream>>>(p3w, wpk + WOFF_P3, 256, 1024, 128);
  pack_w<<<2048, 256, 0, stream>>>(f1w, wpk + WOFF_F1, 1024, 512, 128);
  pack_w<<<64, 256, 0, stream>>>(f2w, wpk + WOFF_F2, 512, 32, 32);

  seg_kernel<<<4000, 256, 0, stream>>>(pairs, ab, bb, p1b, p2b, wpk,
                                       wpk + WOFF_PS);
  combine_kernel<<<8000, 256, 0, stream>>>(wpk + WOFF_PS, idxp, p3b,
                                           wpk + WOFF_HP);
  head_kernel<<<125, 256, 0, stream>>>(wpk, wpk + WOFF_HP, f1b, f2b, f3w, f3b,
                                       (float*)d_out);
}